// Round 6
// baseline (2924.746 us; speedup 1.0000x reference)
//
#include <hip/hip_runtime.h>
#include <hip/hip_fp16.h>

#define T_LEN 192

typedef unsigned long long u64;
typedef _Float16 f16x8 __attribute__((ext_vector_type(8)));
typedef float f32x4 __attribute__((ext_vector_type(4)));

// ---- workspace float offsets ----
#define OFF_X1F   0          // [192][64 tile][16 b][16 row] f32
#define OFF_XPRE  3145728    // [192][16][1024]
#define OFF_XB3   6291456    // x@Ws3 + Ws_b [192][16][256]
#define OFF_HSB   7077888    // hs [16][192][256]
#define OFF_RECA  7864320    // u64[16][8][144]  (h pairs 16 + hp pairs 128)
#define OFF_RECB  7901184    // u64[16][8][513]  (pp pairs 512 + Lp)
#define OFF_HX    8032512    // u64[2][2][512]   lstm h exchange
#define OFF_FLG   8036608    // u32: flgA[128] flgB[128] flgL[4]
#define FLG_WORDS 260

// ---- task LDS byte offsets (main loop) ----
#define L_WCH   0        // u32[128][132]  Wc h-part slice
#define L_G2    67584    // u32[1024][13]  G2[lg][tp pairs]
#define L_WS2   120832   // u32[256][17]   Ws2 k-slice
#define L_BS    138240   // u32[24][129]   base own-tp f16 pairs
#define L_HN2   150624   // u32[16]
#define L_MSC   150688   // f32[4]
#define L_LPS   150704   // f32[8] (pad)
#define L_H2L   150752   // u32[128]
#define L_HTRM  151264   // f32[256]
#define L_EF    152288   // f32[24]
#define L_SCR   152384   // 8448 B: SCRA float2[8][132] | SCRB float[8][132]+PREL
#define L_PREL  156608   // f32[4][132] (inside SCR region, disjoint phase)
#define L_XPL   160832   // f32[128]
#define L_PPS   161344   // f32[128]
#define L_USL   161856   // f32[256]
#define SMEM_TASK 162880
// ---- prologue aliases ----
#define P_HSL   0        // u32[192][128]
#define P_CHK1  98304    // u32[32][128]
#define P_CHK2  98304    // u32[64][128]
#define P_BF    114688   // f32[24][257]

__device__ __forceinline__ unsigned packh2(float a, float b){
  union { __half2 h; unsigned u; } v;
  v.h = __halves2half2(__float2half(a), __float2half(b));
  return v.u;
}
__device__ __forceinline__ float2 unp2(unsigned u){
  union { unsigned u32; __half2 h; } v; v.u32 = u;
  return __half22float2(v.h);
}
__device__ __forceinline__ float fdot2(unsigned a, unsigned b, float c){
#if __has_builtin(__builtin_amdgcn_fdot2)
  typedef _Float16 h2t __attribute__((ext_vector_type(2)));
  union { unsigned u; h2t h; } ua, ub;
  ua.u = a; ub.u = b;
  return __builtin_amdgcn_fdot2(ua.h, ub.h, c, false);
#else
  float2 x = unp2(a), y = unp2(b);
  return c + x.x*y.x + x.y*y.y;
#endif
}
__device__ __forceinline__ float tanh_f(float x){
  float cx = fminf(fmaxf(x, -15.f), 15.f);
  float e = __expf(2.f * cx);
  return (e - 1.f) / (e + 1.f);
}
__device__ __forceinline__ float sigm(float x){
  float cx = fminf(fmaxf(x, -30.f), 30.f);
  return 1.f / (1.f + __expf(-cx));
}
__device__ __forceinline__ u64 gld64(const u64* p){
  return __hip_atomic_load(p, __ATOMIC_RELAXED, __HIP_MEMORY_SCOPE_AGENT);
}
__device__ __forceinline__ void gst64(u64* p, u64 v){
  __hip_atomic_store(p, v, __ATOMIC_RELAXED, __HIP_MEMORY_SCOPE_AGENT);
}
__device__ __forceinline__ unsigned gldu(const unsigned* p){
  return __hip_atomic_load(p, __ATOMIC_RELAXED, __HIP_MEMORY_SCOPE_AGENT);
}
__device__ __forceinline__ void gstu(unsigned* p, unsigned v){
  __hip_atomic_store(p, v, __ATOMIC_RELAXED, __HIP_MEMORY_SCOPE_AGENT);
}
__device__ __forceinline__ u64 mk2(float a, float b){
  return ((u64)__float_as_uint(b) << 32) | (u64)__float_as_uint(a);
}
__device__ __forceinline__ float lof(u64 v){ return __uint_as_float((unsigned)v); }
__device__ __forceinline__ float hif(u64 v){ return __uint_as_float((unsigned)(v >> 32)); }

__global__ __launch_bounds__(256) void initk(float* p, int n){
  int i = blockIdx.x * blockDim.x + threadIdx.x;
  int stride = gridDim.x * blockDim.x;
  for (; i < n; i += stride) p[i] = 0.f;
}

// fused x-projections: bx<32 -> X1F (MFMA layout), bx<64 -> xpre, else xb3
__global__ __launch_bounds__(256) void proj3(const float* __restrict__ x,
                                             const float* __restrict__ W_ih,
                                             const float* __restrict__ b_l,
                                             const float* __restrict__ Wc,
                                             const float* __restrict__ bc,
                                             const float* __restrict__ Ws_w,
                                             const float* __restrict__ Ws_b,
                                             float* __restrict__ ws){
  __shared__ float As[16 * 258];
  __shared__ float Wsh[256 * 34];
  const int bx = blockIdx.x, t = blockIdx.y, tid = threadIdx.x;
  const float* W; const float* bias; int ldw, woff, c0, mode; float* out;
  if (bx < 32)      { W = W_ih; bias = b_l;  ldw = 256; woff = 0;   c0 = bx * 32;        mode = 0; out = ws + OFF_X1F; }
  else if (bx < 64) { W = Wc;   bias = bc;   ldw = 768; woff = 0;   c0 = (bx - 32) * 32; mode = 1; out = ws + OFF_XPRE; }
  else              { W = Ws_w; bias = Ws_b; ldw = 768; woff = 512; c0 = (bx - 64) * 32; mode = 2; out = ws + OFF_XB3; }

  for (int i = 0; i < 16; ++i)
    As[i * 258 + tid] = x[(t * 16 + i) * 256 + tid];
  for (int i = 0; i < 32; ++i)
    Wsh[tid * 34 + i] = W[(c0 + i) * ldw + woff + tid];
  __syncthreads();

  const int r = tid >> 4;
  const int c2 = (tid & 15) * 2;
  float acc0 = 0.f, acc1 = 0.f;
  for (int k = 0; k < 256; k += 2) {
    float2 a  = *(const float2*)&As[r * 258 + k];
    float2 w0 = *(const float2*)&Wsh[k * 34 + c2];
    float2 w1 = *(const float2*)&Wsh[(k + 1) * 34 + c2];
    acc0 = fmaf(a.x, w0.x, acc0); acc0 = fmaf(a.y, w1.x, acc0);
    acc1 = fmaf(a.x, w0.y, acc1); acc1 = fmaf(a.y, w1.y, acc1);
  }
  const int cg = c0 + c2;
  acc0 += bias[cg]; acc1 += bias[cg + 1];
  float2 res; res.x = acc0; res.y = acc1;
  if (mode == 0) {
    *(float2*)&out[((t * 64 + (cg >> 4)) * 16 + r) * 16 + (cg & 15)] = res;
  } else if (mode == 1) {
    *(float2*)&out[(t * 16 + r) * 1024 + cg] = res;
  } else {
    *(float2*)&out[(t * 16 + r) * 256 + cg] = res;
  }
}

// ============ LSTM: 2 WGs (bids 0,8) x 512, W_hh in VGPRs, k-split pipeline ===
__global__ __launch_bounds__(512) void lstm_kernel(const float* __restrict__ X1F,
                                                   const float* __restrict__ W_hh,
                                                   float* __restrict__ hsB,
                                                   u64* __restrict__ hx,
                                                   unsigned* __restrict__ flgL){
  const int bid = blockIdx.x;
  if (bid != 0 && bid != 8) return;
  __shared__ unsigned hT[16 * 136];
  const int tid = threadIdx.x;
  const int wg = (bid == 8) ? 1 : 0;
  const int wave = tid >> 6, lane = tid & 63;
  const int b16 = lane & 15, quad = lane >> 4;
  const int jb = wg * 8 + wave;
  const int peer = 1 - wg;
  const int peer0 = peer * 128;

  f16x8 wf[4][8];
  #pragma unroll
  for (int g = 0; g < 4; ++g) {
    #pragma unroll
    for (int kk = 0; kk < 8; ++kk) {
      int row = g * 256 + jb * 16 + b16;
      const float* wp = &W_hh[row * 256 + kk * 32 + quad * 8];
      f16x8 v;
      #pragma unroll
      for (int j = 0; j < 8; ++j) v[j] = (_Float16)wp[j];
      wf[g][kk] = v;
    }
  }
  for (int i = tid; i < 16 * 136; i += 512) hT[i] = 0u;
  float cst[4] = {0.f, 0.f, 0.f, 0.f};
  __syncthreads();

  for (int t = 0; t < T_LEN; ++t) {
    float4 xi[4];
    #pragma unroll
    for (int g = 0; g < 4; ++g)
      xi[g] = *(const float4*)&X1F[((t * 64 + g * 16 + jb) * 16 + b16) * 16 + quad * 4];

    f32x4 acc[4];
    #pragma unroll
    for (int g = 0; g < 4; ++g) {
      f32x4 a; a[0]=xi[g].x; a[1]=xi[g].y; a[2]=xi[g].z; a[3]=xi[g].w;
      acc[g] = a;
    }
    // chunk A: own k-half (hT own rows written at t-1 epilogue, barrier'd)
    #pragma unroll
    for (int kc = 0; kc < 4; ++kc) {
      int kk = wg * 4 + kc;
      union { uint4 u; f16x8 h; } bv;
      bv.u = *(const uint4*)&hT[b16 * 136 + kk * 16 + quad * 4];
      #pragma unroll
      for (int g = 0; g < 4; ++g)
        acc[g] = __builtin_amdgcn_mfma_f32_16x16x32_f16(wf[g][kk], bv.h, acc[g], 0, 0, 0);
    }
    // poll peer h(t-1) via scout flag, then bulk read once
    if (t > 0) {
      if (tid == 0)
        while ((int)gldu(&flgL[((t - 1) & 1) * 2 + peer]) < t) {}
      __syncthreads();
      u64 v = gld64(&hx[(u64)((t - 1) & 1) * 1024 + peer * 512 + tid]);
      int k2 = (peer0 >> 1) + (tid >> 4) * 2;
      hT[(tid & 15) * 136 + k2]     = (unsigned)v;
      hT[(tid & 15) * 136 + k2 + 1] = (unsigned)(v >> 32);
      __syncthreads();
    }
    // chunk B: peer k-half
    #pragma unroll
    for (int kc = 0; kc < 4; ++kc) {
      int kk = peer * 4 + kc;
      union { uint4 u; f16x8 h; } bv;
      bv.u = *(const uint4*)&hT[b16 * 136 + kk * 16 + quad * 4];
      #pragma unroll
      for (int g = 0; g < 4; ++g)
        acc[g] = __builtin_amdgcn_mfma_f32_16x16x32_f16(wf[g][kk], bv.h, acc[g], 0, 0, 0);
    }
    __syncthreads();   // all hT reads done before epilogue overwrites own rows

    float hv[4];
    #pragma unroll
    for (int r = 0; r < 4; ++r) {
      float cn = fmaf(sigm(acc[1][r]), cst[r], sigm(acc[0][r]) * tanh_f(acc[2][r]));
      hv[r] = sigm(acc[3][r]) * tanh_f(cn);
      cst[r] = cn;
    }
    int j0 = jb * 16 + quad * 4;
    *(float4*)&hsB[(b16 * 192 + t) * 256 + j0] = make_float4(hv[0], hv[1], hv[2], hv[3]);
    hT[b16 * 136 + (j0 >> 1)]     = packh2(hv[0], hv[1]);
    hT[b16 * 136 + (j0 >> 1) + 1] = packh2(hv[2], hv[3]);
    u64 w64 = ((u64)packh2(hv[2], hv[3]) << 32) | (u64)packh2(hv[0], hv[1]);
    gst64(&hx[(u64)(t & 1) * 1024 + wg * 512 + ((j0 - wg * 128) >> 2) * 16 + b16], w64);
    __syncthreads();   // drains hx/hsB stores (vmcnt0 before barrier) + orders hT
    if (tid == 0) gstu(&flgL[(t & 1) * 2 + wg], (unsigned)(t + 1));
  }
}

// ============ task: 128 WGs x 512; 2 scout-flag exchanges/step ================
__global__ __launch_bounds__(512) void task_kernel(
    const float* __restrict__ xb3, const float* __restrict__ xpre,
    const float* __restrict__ hsB, const float* __restrict__ Us_w,
    const float* __restrict__ Us_b, const float* __restrict__ Wc,
    const float* __restrict__ Ws_w,
    u64* __restrict__ RECA, u64* __restrict__ RECB,
    unsigned* __restrict__ flgA, unsigned* __restrict__ flgB,
    float* __restrict__ out){
  extern __shared__ char smem[];
  unsigned* WCHu = (unsigned*)(smem + L_WCH);
  unsigned* G2u  = (unsigned*)(smem + L_G2);
  unsigned* WS2u = (unsigned*)(smem + L_WS2);
  unsigned* BSu  = (unsigned*)(smem + L_BS);
  unsigned* HN2  = (unsigned*)(smem + L_HN2);
  float* MSC     = (float*)(smem + L_MSC);
  float* LPS     = (float*)(smem + L_LPS);
  unsigned* H2L  = (unsigned*)(smem + L_H2L);
  float* HTRM    = (float*)(smem + L_HTRM);
  float* EF      = (float*)(smem + L_EF);
  float2* SCRA   = (float2*)(smem + L_SCR);
  float* SCRB    = (float*)(smem + L_SCR);
  float* PREL    = (float*)(smem + L_PREL);
  float* XPL     = (float*)(smem + L_XPL);
  float* PPS     = (float*)(smem + L_PPS);
  float* USL     = (float*)(smem + L_USL);
  unsigned* HSL  = (unsigned*)(smem + P_HSL);
  unsigned* CHK1 = (unsigned*)(smem + P_CHK1);
  unsigned* CHK2 = (unsigned*)(smem + P_CHK2);
  float* BF      = (float*)(smem + P_BF);

  const int tid = threadIdx.x;
  const int bb = blockIdx.x & 15;
  const int s  = blockIdx.x >> 4;
  const int wave = tid >> 6, lane = tid & 63;
  const int m16 = lane & 15, quad = lane >> 4;

  // ---- P1: hs (f16 pairs), USL ----
  for (int i = tid; i < 24576; i += 512) {
    int tp = i >> 7, k2 = i & 127;
    const float* hp = &hsB[(bb * 192 + tp) * 256 + 2 * k2];
    HSL[i] = packh2(hp[0], hp[1]);
  }
  if (tid < 256) USL[tid] = Us_w[tid];
  const float usb = Us_b[0];
  __syncthreads();

  // ---- P2: base = xb3 + hs @ Ws1^T for own 24 tp (MFMA, 8 c-chunks) ----
  for (int cc = 0; cc < 8; ++cc) {
    for (int i = tid; i < 4096; i += 512) {
      int cl = i >> 7, k2 = i & 127;
      const float* wp = &Ws_w[(cc * 32 + cl) * 768 + 2 * k2];
      CHK1[i] = packh2(wp[0], wp[1]);
    }
    __syncthreads();
    if (wave < 4) {
      int tt = wave & 1, lt = wave >> 1;
      int col = cc * 32 + lt * 16 + m16;
      f32x4 a;
      #pragma unroll
      for (int rr = 0; rr < 4; ++rr)
        a[rr] = xb3[((24 * s + tt * 8 + quad * 4 + rr) * 16 + bb) * 256 + col];
      #pragma unroll
      for (int kk = 0; kk < 8; ++kk) {
        union { uint4 u; f16x8 h; } av, bv;
        av.u = *(const uint4*)&HSL[(24 * s + tt * 8 + m16) * 128 + kk * 16 + quad * 4];
        bv.u = *(const uint4*)&CHK1[(lt * 16 + m16) * 128 + kk * 16 + quad * 4];
        a = __builtin_amdgcn_mfma_f32_16x16x32_f16(av.h, bv.h, a, 0, 0, 0);
      }
      #pragma unroll
      for (int rr = 0; rr < 4; ++rr) {
        int tpl = tt * 8 + quad * 4 + rr;
        if (tt == 0 || tpl >= 16) BF[tpl * 257 + col] = a[rr];
      }
    }
    __syncthreads();
  }
  // pack BF f32 -> BS f16 pairs (read-all / barrier / write, overlapping ok)
  {
    float pa[6], pb[6];
    #pragma unroll
    for (int ii = 0; ii < 6; ++ii) {
      int i = tid + ii * 512;
      int tp = i >> 7, c2 = i & 127;
      pa[ii] = BF[tp * 257 + 2 * c2];
      pb[ii] = BF[tp * 257 + 2 * c2 + 1];
    }
    __syncthreads();
    #pragma unroll
    for (int ii = 0; ii < 6; ++ii) {
      int i = tid + ii * 512;
      int tp = i >> 7, c2 = i & 127;
      BSu[tp * 129 + c2] = packh2(pa[ii], pb[ii]);
    }
    __syncthreads();
  }

  // ---- P3: G2[lg][own 24 tp] = Wc_R . hs^T  (16 chunks, frags in regs) ----
  f32x4 gacc[16];
  const int lt3 = wave >> 1, tt3 = wave & 1;
  for (int ci = 0; ci < 16; ++ci) {
    for (int i = tid; i < 8192; i += 512) {
      int rr = i >> 7, k2 = i & 127;
      int lg = ci * 64 + rr;
      int row = ((lg >> 5) & 3) * 256 + 32 * (lg >> 7) + (lg & 31);
      const float* wp = &Wc[row * 768 + 256 + 2 * k2];
      CHK2[i] = packh2(wp[0], wp[1]);
    }
    __syncthreads();
    {
      f32x4 a; a[0] = 0.f; a[1] = 0.f; a[2] = 0.f; a[3] = 0.f;
      int hr = 24 * s + tt3 * 16 + m16;
      if (hr > 191) hr = 191;
      #pragma unroll
      for (int kk = 0; kk < 8; ++kk) {
        union { uint4 u; f16x8 h; } av, bv;
        av.u = *(const uint4*)&CHK2[(lt3 * 16 + m16) * 128 + kk * 16 + quad * 4];
        bv.u = *(const uint4*)&HSL[hr * 128 + kk * 16 + quad * 4];
        a = __builtin_amdgcn_mfma_f32_16x16x32_f16(av.h, bv.h, a, 0, 0, 0);
      }
      gacc[ci] = a;
    }
    __syncthreads();
  }
  // ---- write G2 + fill WCH, WS2 (hsL/CHK dead) ----
  #pragma unroll
  for (int ci = 0; ci < 16; ++ci) {
    #pragma unroll
    for (int r = 0; r < 4; ++r) {
      float v = gacc[ci][r];
      float vn = __shfl_xor(v, 1);
      bool wr = ((lane & 1) == 0) && (tt3 == 0 ? true : (m16 < 8));
      if (wr) {
        int lgg = ci * 64 + lt3 * 16 + quad * 4 + r;
        int jp = tt3 * 8 + (m16 >> 1);
        G2u[lgg * 13 + jp] = packh2(v, vn);
      }
    }
  }
  for (int i = tid; i < 16384; i += 512) {
    int l = i >> 7, k2 = i & 127;
    int row = (l >> 5) * 256 + 32 * s + (l & 31);
    const float* wp = &Wc[row * 768 + 512 + 2 * k2];
    WCHu[l * 132 + k2] = packh2(wp[0], wp[1]);
  }
  for (int i = tid; i < 4096; i += 512) {
    int c = i >> 4, k2 = i & 15;
    const float* wp = &Ws_w[c * 768 + 256 + 32 * s + 2 * k2];
    WS2u[c * 17 + k2] = packh2(wp[0], wp[1]);
  }
  __syncthreads();

  const u64* ra0 = RECA + (u64)bb * 8 * 144;
  u64* raMY = RECA + ((u64)bb * 8 + s) * 144;
  u64* rbMY = RECB + ((u64)bb * 8 + s) * 513;
  const uint4* WP4 = (const uint4*)WCHu;
  const uint4* H2P = (const uint4*)H2L;
  float creg = 0.f;

  for (int t = 0; t < T_LEN; ++t) {
    if (tid < 128)
      XPL[tid] = xpre[(t * 16 + bb) * 1024 + (tid >> 5) * 256 + 32 * s + (tid & 31)];

    // ---- exchange 1: h(t-1) + hterm partials ----
    if (t == 0) {
      if (tid < 128) H2L[tid] = 0u;
      if (tid < 256) HTRM[tid] = 0.f;
      __syncthreads();
    } else {
      if (tid < 8) while ((int)gldu(&flgA[bb * 8 + tid]) < t) {}
      __syncthreads();
      {
        int s1 = tid >> 6, p = tid & 63;
        u64 v1 = gld64(&ra0[s1 * 144 + 16 + p]);
        u64 v2 = gld64(&ra0[s1 * 144 + 80 + p]);
        SCRA[s1 * 132 + p]      = make_float2(lof(v1), hif(v1));
        SCRA[s1 * 132 + 64 + p] = make_float2(lof(v2), hif(v2));
        if (tid < 128) {
          u64 vh = gld64(&ra0[(tid >> 4) * 144 + (tid & 15)]);
          H2L[tid] = packh2(lof(vh), hif(vh));
        }
      }
      __syncthreads();
      if (tid < 128) {
        float ax = 0.f, ay = 0.f;
        #pragma unroll
        for (int s8 = 0; s8 < 8; ++s8) {
          float2 t2 = SCRA[s8 * 132 + tid];
          ax += t2.x; ay += t2.y;
        }
        HTRM[2 * tid] = ax; HTRM[2 * tid + 1] = ay;
      }
      __syncthreads();
    }

    // ---- scores for own 24 tp (local, no exchange) ----
    {
      float4 h4 = *(const float4*)&HTRM[lane * 4];
      float4 u4 = *(const float4*)&USL[lane * 4];
      float p[3];
      #pragma unroll
      for (int j = 0; j < 3; ++j) {
        int tpl = wave * 3 + j;
        float2 f0 = unp2(BSu[tpl * 129 + lane * 2]);
        float2 f1 = unp2(BSu[tpl * 129 + lane * 2 + 1]);
        p[j] = u4.x * tanh_f(f0.x + h4.x) + u4.y * tanh_f(f0.y + h4.y)
             + u4.z * tanh_f(f1.x + h4.z) + u4.w * tanh_f(f1.y + h4.w);
      }
      #pragma unroll
      for (int off = 32; off >= 1; off >>= 1) {
        p[0] += __shfl_xor(p[0], off);
        p[1] += __shfl_xor(p[1], off);
        p[2] += __shfl_xor(p[2], off);
      }
      if (lane == 0) {
        EF[wave * 3 + 0] = __expf(p[0] + usb);
        EF[wave * 3 + 1] = __expf(p[1] + usb);
        EF[wave * 3 + 2] = __expf(p[2] + usb);
      }
    }
    __syncthreads();

    // ---- pp[lg] = sum_own-tp e*G2 for all 1024 lg; publish ----
    {
      float ev[24];
      #pragma unroll
      for (int j = 0; j < 6; ++j) {
        float4 q = ((const float4*)EF)[j];
        ev[4*j] = q.x; ev[4*j+1] = q.y; ev[4*j+2] = q.z; ev[4*j+3] = q.w;
      }
      float pp0 = 0.f, pp1 = 0.f;
      #pragma unroll
      for (int j = 0; j < 12; ++j) {
        float2 g0 = unp2(G2u[tid * 13 + j]);
        float2 g1 = unp2(G2u[(tid + 512) * 13 + j]);
        pp0 = fmaf(g0.x, ev[2*j], pp0); pp0 = fmaf(g0.y, ev[2*j+1], pp0);
        pp1 = fmaf(g1.x, ev[2*j], pp1); pp1 = fmaf(g1.y, ev[2*j+1], pp1);
      }
      gst64(&rbMY[tid], mk2(pp0, pp1));
      if (tid == 0) {
        float Lp = 0.f;
        #pragma unroll
        for (int q = 0; q < 24; ++q) Lp += ev[q];
        gst64(&rbMY[512], mk2(Lp, 0.f));
      }
    }
    __syncthreads();               // drain publish
    if (tid == 0) gstu(&flgB[bb * 8 + s], (unsigned)(t + 1));

    // ---- exchange 2: pp partials ----
    if (tid < 8) while ((int)gldu(&flgB[bb * 8 + tid]) < t + 1) {}
    __syncthreads();
    {
      int s1 = tid >> 6, k = tid & 63;
      const u64* rb1 = RECB + ((u64)bb * 8 + s1) * 513;
      int wb = 128 * (s & 3);
      u64 v1 = gld64(&rb1[wb + k]);
      u64 v2 = gld64(&rb1[wb + 64 + k]);
      SCRB[s1 * 132 + k]      = (s < 4) ? lof(v1) : hif(v1);
      SCRB[s1 * 132 + 64 + k] = (s < 4) ? lof(v2) : hif(v2);
      if (tid < 8) {
        u64 lv = gld64(&(RECB + ((u64)bb * 8 + tid) * 513)[512]);
        LPS[tid] = lof(lv);
      }
    }
    __syncthreads();
    if (tid < 128) {
      float a = 0.f;
      #pragma unroll
      for (int s8 = 0; s8 < 8; ++s8) a += SCRB[s8 * 132 + tid];
      PPS[tid] = a;
    }
    if (tid == 0) {
      float L = 0.f;
      #pragma unroll
      for (int i = 0; i < 8; ++i) L += LPS[i];
      MSC[0] = 1.f / L;
    }
    // gates GEMV (Wch . h): l = tid&127, K-quarter = tid>>7
    {
      int l = tid & 127, q = tid >> 7;
      float a = 0.f;
      #pragma unroll
      for (int i = 0; i < 8; ++i) {
        uint4 w4 = WP4[l * 33 + q * 8 + i];
        uint4 h4 = H2P[q * 8 + i];
        a = fdot2(w4.x, h4.x, a); a = fdot2(w4.y, h4.y, a);
        a = fdot2(w4.z, h4.z, a); a = fdot2(w4.w, h4.w, a);
      }
      PREL[q * 132 + l] = a;
    }
    __syncthreads();

    // ---- gates + h publish ----
    if (tid < 32) {
      int jl = tid;
      float inv = MSC[0];
      float pr[4];
      #pragma unroll
      for (int g = 0; g < 4; ++g) {
        int ix = g * 32 + jl;
        pr[g] = XPL[ix] + PPS[ix] * inv
              + PREL[ix] + PREL[132 + ix] + PREL[264 + ix] + PREL[396 + ix];
      }
      float cn = fmaf(sigm(pr[1]), creg, sigm(pr[0]) * tanh_f(pr[2]));
      float h = sigm(pr[3]) * tanh_f(cn);
      creg = cn;
      out[(bb * 192 + t) * 256 + 32 * s + jl] = h;
      float hn = __shfl_down(h, 1);
      if ((jl & 1) == 0) {
        HN2[jl >> 1] = packh2(h, hn);
        gst64(&raMY[jl >> 1], mk2(h, hn));
      }
    }
    __syncthreads();

    // ---- hterm partial from own h-slice; publish ----
    if (tid < 256) {
      float a = 0.f;
      #pragma unroll
      for (int i = 0; i < 16; ++i)
        a = fdot2(WS2u[tid * 17 + i], HN2[i], a);
      float an = __shfl_down(a, 1);
      if ((tid & 1) == 0) gst64(&raMY[16 + (tid >> 1)], mk2(a, an));
    }
    __syncthreads();               // drain recA stores
    if (tid == 0) gstu(&flgA[bb * 8 + s], (unsigned)(t + 1));
  }
}

extern "C" void kernel_launch(void* const* d_in, const int* in_sizes, int n_in,
                              void* d_out, int out_size, void* d_ws, size_t ws_size,
                              hipStream_t stream) {
  (void)in_sizes; (void)n_in; (void)out_size; (void)ws_size;
  const float* x    = (const float*)d_in[0];
  const float* W_ih = (const float*)d_in[1];
  const float* W_hh = (const float*)d_in[2];
  const float* b_l  = (const float*)d_in[3];
  const float* Ws_w = (const float*)d_in[4];
  const float* Ws_b = (const float*)d_in[5];
  const float* Us_w = (const float*)d_in[6];
  const float* Us_b = (const float*)d_in[7];
  const float* Wc   = (const float*)d_in[8];
  const float* bc   = (const float*)d_in[9];
  float* out = (float*)d_out;
  float* ws = (float*)d_ws;

  hipFuncSetAttribute((const void*)task_kernel,
                      hipFuncAttributeMaxDynamicSharedMemorySize, 160 * 1024);

  unsigned* flg = (unsigned*)(ws + OFF_FLG);

  // zero flags only (payloads are flag-gated)
  initk<<<1, 256, 0, stream>>>(ws + OFF_FLG, FLG_WORDS);

  // x-projections
  proj3<<<dim3(72, 192), 256, 0, stream>>>(x, W_ih, b_l, Wc, bc, Ws_w, Ws_b, ws);

  // shared LSTM (bids 0,8 active -> same-XCD heuristic)
  lstm_kernel<<<9, 512, 0, stream>>>(ws + OFF_X1F, W_hh, ws + OFF_HSB,
                                     (u64*)(ws + OFF_HX), flg + 256);

  // task loop
  task_kernel<<<128, 512, SMEM_TASK, stream>>>(
      ws + OFF_XB3, ws + OFF_XPRE, ws + OFF_HSB, Us_w, Us_b, Wc, Ws_w,
      (u64*)(ws + OFF_RECA), (u64*)(ws + OFF_RECB), flg, flg + 128, out);
}